// Round 6
// baseline (299.638 us; speedup 1.0000x reference)
//
#include <hip/hip_runtime.h>
#include <hip/hip_bf16.h>

#define T_LOCAL 2048
#define S_GLOBAL 4096
#define NQ 16
#define NK 8
#define HN 128

// 128^-0.5 * log2(e)
#define SCALE2 0.12753102541996022f

typedef __attribute__((ext_vector_type(8))) short short8;
typedef __attribute__((ext_vector_type(4))) float f32x4;

static __device__ __forceinline__ ushort f2bf(float x) {
  unsigned u = __builtin_bit_cast(unsigned, x);
  unsigned r = (u + 0x7fffu + ((u >> 16) & 1u)) >> 16;
  return (ushort)r;
}

// ---- pre-pass 1: K f32 -> bf16 (same layout [S][NK][HN]) ----
__global__ void k_convert(const float* __restrict__ K, ushort* __restrict__ Kb) {
  size_t i = ((size_t)blockIdx.x * 256 + threadIdx.x) * 4;
  float4 v = *(const float4*)(K + i);
  ushort4 o;
  o.x = f2bf(v.x); o.y = f2bf(v.y); o.z = f2bf(v.z); o.w = f2bf(v.w);
  *(ushort4*)(Kb + i) = o;
}

// ---- pre-pass 2: V f32 [S][NK][HN] -> Vt bf16 [NK][HN][S] (per-head transpose) ----
__global__ void v_transpose(const float* __restrict__ V, ushort* __restrict__ Vt) {
  int bid = blockIdx.x;            // 8 heads * 2 d-tiles * 64 p-tiles = 1024
  int h  = bid >> 7;
  int r  = bid & 127;
  int d0 = (r >> 6) << 6;          // 0 or 64
  int p0 = (r & 63) << 6;          // 0..4032
  __shared__ ushort tile[64][72];  // [d_local][p_local], padded
  int tx = threadIdx.x & 15, ty = threadIdx.x >> 4;
  #pragma unroll
  for (int it = 0; it < 4; ++it) {
    int p = p0 + it * 16 + ty;
    int d = tx * 4;
    float4 v = *(const float4*)(V + ((size_t)p * NK + h) * HN + d0 + d);
    tile[d + 0][it * 16 + ty] = f2bf(v.x);
    tile[d + 1][it * 16 + ty] = f2bf(v.y);
    tile[d + 2][it * 16 + ty] = f2bf(v.z);
    tile[d + 3][it * 16 + ty] = f2bf(v.w);
  }
  __syncthreads();
  #pragma unroll
  for (int it = 0; it < 4; ++it) {
    int d  = it * 16 + ty;
    int pb = tx * 4;
    ushort4 o;
    o.x = tile[d][pb + 0]; o.y = tile[d][pb + 1];
    o.z = tile[d][pb + 2]; o.w = tile[d][pb + 3];
    *(ushort4*)(Vt + ((size_t)h * HN + d0 + d) * S_GLOBAL + p0 + pb) = o;
  }
}

// ---- main attention kernel ----
// grid: 16 heads * 128 q-tiles(16 rows) = 2048 blocks, 256 threads (4 waves).
// All 4 waves share one 16-row q-tile; wave w handles key-steps s = w, w+4, ...
// (split-K). Partial (m,l,O) merged across waves via LDS at the end.
__global__ __launch_bounds__(256, 8)
void attn_kernel(const float* __restrict__ Q, const ushort* __restrict__ Kb,
                 const ushort* __restrict__ Vt, float* __restrict__ Out) {
  __shared__ ushort Pl[4][16][56];   // per-wave P^T staging
  __shared__ float Obuf[16][132];    // merge buffer [q][d], padded
  __shared__ float Ml[2][16];        // merge m,l per q

  const int lane = threadIdx.x & 63;
  const int w    = threadIdx.x >> 6;   // chunk id
  const int qcol = lane & 15;
  const int g    = lane >> 4;

  const int bid  = blockIdx.x;
  const int head = bid >> 7;
  const int kvh  = head >> 1;
  // interleave light (first-half) / heavy (second-half) tiles at period 8 so
  // the XCD round-robin (bid % 8) sees a mix on every XCD.
  const int slot = bid & 127;
  const int lh   = (slot >> 3) & 1;
  const int idx  = ((slot >> 4) << 3) | (slot & 7);   // 0..63
  const int tile = lh ? (64 + idx) : idx;             // 0..127
  const int tw   = tile << 4;
  const int tq   = tw + qcol;        // this lane's q row (local index)

  // Q fragments (B operand: col = q, k-slice = d)
  short8 qf[4];
  {
    const float* qb = Q + ((size_t)tq * NQ + head) * HN;
    #pragma unroll
    for (int ds = 0; ds < 4; ++ds) {
      const float4* p4 = (const float4*)(qb + ds * 32 + g * 8);
      float4 a = p4[0], b = p4[1];
      short8 f;
      f[0] = f2bf(a.x); f[1] = f2bf(a.y); f[2] = f2bf(a.z); f[3] = f2bf(a.w);
      f[4] = f2bf(b.x); f[5] = f2bf(b.y); f[6] = f2bf(b.z); f[7] = f2bf(b.w);
      qf[ds] = f;
    }
  }

  f32x4 acc[8];
  #pragma unroll
  for (int i = 0; i < 8; ++i) acc[i] = (f32x4){0.f, 0.f, 0.f, 0.f};
  float m_run = -1e30f, l_run = 0.f;

  const ushort* Vrow = Vt + (size_t)kvh * HN * S_GLOBAL;
  ushort* prow = &Pl[w][qcol][0];

  auto tile_step = [&](int p0, bool needmask, bool anti) {
    // K A-fragments: row = key (qcol), k-slice = d
    short8 kf[2][4];
    #pragma unroll
    for (int sub = 0; sub < 2; ++sub) {
      const ushort* kp = Kb + ((size_t)(p0 + sub * 16 + qcol) * NK + kvh) * HN + g * 8;
      #pragma unroll
      for (int ds = 0; ds < 4; ++ds)
        kf[sub][ds] = *(const short8*)(kp + ds * 32);
    }
    // V^T A-fragments: row = d (qcol), k-slice = keys
    short8 vf[8];
    #pragma unroll
    for (int db = 0; db < 8; ++db)
      vf[db] = *(const short8*)(Vrow + (size_t)(db * 16 + qcol) * S_GLOBAL + p0 + g * 8);

    // S^T = K * Q^T : D[key][q]
    f32x4 st[2];
    st[0] = (f32x4){0.f, 0.f, 0.f, 0.f};
    st[1] = (f32x4){0.f, 0.f, 0.f, 0.f};
    #pragma unroll
    for (int sub = 0; sub < 2; ++sub)
      #pragma unroll
      for (int ds = 0; ds < 4; ++ds)
        st[sub] = __builtin_amdgcn_mfma_f32_16x16x32_bf16(kf[sub][ds], qf[ds], st[sub], 0, 0, 0);

    float s[8];
    #pragma unroll
    for (int sub = 0; sub < 2; ++sub) {
      #pragma unroll
      for (int r = 0; r < 4; ++r) {
        float sv = st[sub][r] * SCALE2;
        if (needmask) {
          int p = p0 + sub * 16 + g * 4 + r;
          bool ok = anti ? (p >= tq + 2049) : (p <= tq);
          sv = ok ? sv : -INFINITY;
        }
        s[sub * 4 + r] = sv;
      }
    }

    // online softmax (4-lane-group reduce over key axis)
    float mt = s[0];
    #pragma unroll
    for (int i = 1; i < 8; ++i) mt = fmaxf(mt, s[i]);
    mt = fmaxf(mt, __shfl_xor(mt, 16));
    mt = fmaxf(mt, __shfl_xor(mt, 32));
    float mnew = fmaxf(m_run, mt);
    float fsc  = __builtin_amdgcn_exp2f(m_run - mnew);
    float pv[8];
    float ps = 0.f;
    #pragma unroll
    for (int i = 0; i < 8; ++i) { pv[i] = __builtin_amdgcn_exp2f(s[i] - mnew); ps += pv[i]; }
    ps += __shfl_xor(ps, 16);
    ps += __shfl_xor(ps, 32);
    l_run = l_run * fsc + ps;
    m_run = mnew;
    #pragma unroll
    for (int i = 0; i < 8; ++i) acc[i] *= fsc;

    // P^T -> LDS, then read back in B-fragment layout
    unsigned lo0 = (unsigned)f2bf(pv[0]) | ((unsigned)f2bf(pv[1]) << 16);
    unsigned hi0 = (unsigned)f2bf(pv[2]) | ((unsigned)f2bf(pv[3]) << 16);
    unsigned lo1 = (unsigned)f2bf(pv[4]) | ((unsigned)f2bf(pv[5]) << 16);
    unsigned hi1 = (unsigned)f2bf(pv[6]) | ((unsigned)f2bf(pv[7]) << 16);
    *(uint2*)(prow + g * 4)      = make_uint2(lo0, hi0);
    *(uint2*)(prow + 16 + g * 4) = make_uint2(lo1, hi1);
    short8 pf = *(const short8*)(prow + g * 8);

    // O^T += V^T * P^T : D[d][q]
    #pragma unroll
    for (int db = 0; db < 8; ++db)
      acc[db] = __builtin_amdgcn_mfma_f32_16x16x32_bf16(vf[db], pf, acc[db], 0, 0, 0);
  };

  // enumerate this tile's key-steps; wave w takes s = w, w+4, ...
  int cbase, nc, abeg = 0, na = 0;
  if (tw < T_LOCAL / 2) {
    cbase = 0;
    nc = ((tw + 15) >> 5) + 1;
  } else {
    cbase = 1024;
    nc = ((tw + 15 - 1024) >> 5) + 1;
    abeg = (tw + 2049) & ~31;
    na = ((4064 - abeg) >> 5) + 1;
  }
  const int ntot = nc + na;
  for (int s = w; s < ntot; s += 4) {
    if (s < nc) {
      int p0 = cbase + (s << 5);
      tile_step(p0, p0 + 31 > tw, false);
    } else {
      int p0 = abeg + ((s - nc) << 5);
      tile_step(p0, p0 < tw + 2064, true);
    }
  }

  // ---- cross-wave merge (3 serial rounds through one LDS buffer) ----
  #pragma unroll 1
  for (int r = 1; r < 4; ++r) {
    if (w == r) {
      if (g == 0) { Ml[0][qcol] = m_run; Ml[1][qcol] = l_run; }
      #pragma unroll
      for (int db = 0; db < 8; ++db)
        *(f32x4*)&Obuf[qcol][db * 16 + 4 * g] = acc[db];
    }
    __syncthreads();
    if (w == 0) {
      float mr = Ml[0][qcol], lr = Ml[1][qcol];
      float mnew = fmaxf(m_run, mr);
      float f0 = __builtin_amdgcn_exp2f(m_run - mnew);
      float fr = __builtin_amdgcn_exp2f(mr - mnew);
      l_run = l_run * f0 + lr * fr;
      m_run = mnew;
      #pragma unroll
      for (int db = 0; db < 8; ++db) {
        f32x4 o = *(const f32x4*)&Obuf[qcol][db * 16 + 4 * g];
        acc[db] = acc[db] * f0 + o * fr;
      }
    }
    __syncthreads();
  }

  if (w == 0) {
    float inv = 1.0f / l_run;
    float* ob = Out + (size_t)tq * (NQ * HN) + head * HN + g * 4;
    #pragma unroll
    for (int db = 0; db < 8; ++db) {
      float4 o;
      o.x = acc[db][0] * inv; o.y = acc[db][1] * inv;
      o.z = acc[db][2] * inv; o.w = acc[db][3] * inv;
      *(float4*)(ob + db * 16) = o;
    }
  }
}

extern "C" void kernel_launch(void* const* d_in, const int* in_sizes, int n_in,
                              void* d_out, int out_size, void* d_ws, size_t ws_size,
                              hipStream_t stream) {
  const float* Q = (const float*)d_in[0];
  const float* K = (const float*)d_in[1];
  const float* V = (const float*)d_in[2];
  float* Out = (float*)d_out;

  ushort* Kb = (ushort*)d_ws;                         // 8 MB
  ushort* Vt = Kb + (size_t)S_GLOBAL * NK * HN;       // 8 MB

  k_convert<<<dim3((S_GLOBAL * NK * HN) / (256 * 4)), dim3(256), 0, stream>>>(K, Kb);
  v_transpose<<<dim3(NK * 2 * (S_GLOBAL / 64)), dim3(256), 0, stream>>>(V, Vt);
  attn_kernel<<<dim3(16 * 128), dim3(256), 0, stream>>>(Q, Kb, Vt, Out);
}

// Round 7
// 219.737 us; speedup vs baseline: 1.3636x; 1.3636x over previous
//
#include <hip/hip_runtime.h>
#include <hip/hip_bf16.h>

#define T_LOCAL 2048
#define S_GLOBAL 4096
#define NQ 16
#define NK 8
#define HN 128

// 128^-0.5 * log2(e)
#define SCALE2 0.12753102541996022f

typedef __attribute__((ext_vector_type(8))) short short8;
typedef __attribute__((ext_vector_type(4))) float f32x4;

static __device__ __forceinline__ ushort f2bf(float x) {
  unsigned u = __builtin_bit_cast(unsigned, x);
  unsigned r = (u + 0x7fffu + ((u >> 16) & 1u)) >> 16;
  return (ushort)r;
}

// ---- pre-pass 1: K f32 -> bf16 (same layout [S][NK][HN]) ----
__global__ void k_convert(const float* __restrict__ K, ushort* __restrict__ Kb) {
  size_t i = ((size_t)blockIdx.x * 256 + threadIdx.x) * 4;
  float4 v = *(const float4*)(K + i);
  ushort4 o;
  o.x = f2bf(v.x); o.y = f2bf(v.y); o.z = f2bf(v.z); o.w = f2bf(v.w);
  *(ushort4*)(Kb + i) = o;
}

// ---- pre-pass 2: V f32 [S][NK][HN] -> Vt bf16 [NK][HN][S] (per-head transpose) ----
__global__ void v_transpose(const float* __restrict__ V, ushort* __restrict__ Vt) {
  int bid = blockIdx.x;            // 8 heads * 2 d-tiles * 64 p-tiles = 1024
  int h  = bid >> 7;
  int r  = bid & 127;
  int d0 = (r >> 6) << 6;          // 0 or 64
  int p0 = (r & 63) << 6;          // 0..4032
  __shared__ ushort tile[64][72];  // [d_local][p_local], padded
  int tx = threadIdx.x & 15, ty = threadIdx.x >> 4;
  #pragma unroll
  for (int it = 0; it < 4; ++it) {
    int p = p0 + it * 16 + ty;
    int d = tx * 4;
    float4 v = *(const float4*)(V + ((size_t)p * NK + h) * HN + d0 + d);
    tile[d + 0][it * 16 + ty] = f2bf(v.x);
    tile[d + 1][it * 16 + ty] = f2bf(v.y);
    tile[d + 2][it * 16 + ty] = f2bf(v.z);
    tile[d + 3][it * 16 + ty] = f2bf(v.w);
  }
  __syncthreads();
  #pragma unroll
  for (int it = 0; it < 4; ++it) {
    int d  = it * 16 + ty;
    int pb = tx * 4;
    ushort4 o;
    o.x = tile[d][pb + 0]; o.y = tile[d][pb + 1];
    o.z = tile[d][pb + 2]; o.w = tile[d][pb + 3];
    *(ushort4*)(Vt + ((size_t)h * HN + d0 + d) * S_GLOBAL + p0 + pb) = o;
  }
}

// ---- main attention kernel ----
// grid: 16 heads * 128 q-tiles(16 rows) = 2048 blocks, 256 threads (4 waves).
// All 4 waves share one 16-row q-tile; wave w handles key-steps s = w, w+4, ...
// (split-K). Partial (m,l,O) merged across waves via LDS at the end.
// launch_bounds(256,4): 128-VGPR budget — (256,8) forced 32 VGPRs and spilled
// everything to scratch (420 MB HBM traffic, 215 us). 16 waves/CU is plenty.
__global__ __launch_bounds__(256, 4)
void attn_kernel(const float* __restrict__ Q, const ushort* __restrict__ Kb,
                 const ushort* __restrict__ Vt, float* __restrict__ Out) {
  __shared__ ushort Pl[4][16][56];   // per-wave P^T staging
  __shared__ float Obuf[16][132];    // merge buffer [q][d], padded
  __shared__ float Ml[2][16];        // merge m,l per q

  const int lane = threadIdx.x & 63;
  const int w    = threadIdx.x >> 6;   // chunk id
  const int qcol = lane & 15;
  const int g    = lane >> 4;

  const int bid  = blockIdx.x;
  const int head = bid >> 7;
  const int kvh  = head >> 1;
  // interleave light (first-half) / heavy (second-half) tiles at period 8 so
  // the XCD round-robin (bid % 8) sees a mix on every XCD.
  const int slot = bid & 127;
  const int lh   = (slot >> 3) & 1;
  const int idx  = ((slot >> 4) << 3) | (slot & 7);   // 0..63
  const int tile = lh ? (64 + idx) : idx;             // 0..127
  const int tw   = tile << 4;
  const int tq   = tw + qcol;        // this lane's q row (local index)

  // Q fragments (B operand: col = q, k-slice = d)
  short8 qf[4];
  {
    const float* qb = Q + ((size_t)tq * NQ + head) * HN;
    #pragma unroll
    for (int ds = 0; ds < 4; ++ds) {
      const float4* p4 = (const float4*)(qb + ds * 32 + g * 8);
      float4 a = p4[0], b = p4[1];
      short8 f;
      f[0] = f2bf(a.x); f[1] = f2bf(a.y); f[2] = f2bf(a.z); f[3] = f2bf(a.w);
      f[4] = f2bf(b.x); f[5] = f2bf(b.y); f[6] = f2bf(b.z); f[7] = f2bf(b.w);
      qf[ds] = f;
    }
  }

  f32x4 acc[8];
  #pragma unroll
  for (int i = 0; i < 8; ++i) acc[i] = (f32x4){0.f, 0.f, 0.f, 0.f};
  float m_run = -1e30f, l_run = 0.f;

  const ushort* Vrow = Vt + (size_t)kvh * HN * S_GLOBAL;
  ushort* prow = &Pl[w][qcol][0];

  auto tile_step = [&](int p0, bool needmask, bool anti) {
    // K A-fragments: row = key (qcol), k-slice = d
    short8 kf[2][4];
    #pragma unroll
    for (int sub = 0; sub < 2; ++sub) {
      const ushort* kp = Kb + ((size_t)(p0 + sub * 16 + qcol) * NK + kvh) * HN + g * 8;
      #pragma unroll
      for (int ds = 0; ds < 4; ++ds)
        kf[sub][ds] = *(const short8*)(kp + ds * 32);
    }
    // V^T A-fragments: row = d (qcol), k-slice = keys
    short8 vf[8];
    #pragma unroll
    for (int db = 0; db < 8; ++db)
      vf[db] = *(const short8*)(Vrow + (size_t)(db * 16 + qcol) * S_GLOBAL + p0 + g * 8);

    // S^T = K * Q^T : D[key][q]
    f32x4 st[2];
    st[0] = (f32x4){0.f, 0.f, 0.f, 0.f};
    st[1] = (f32x4){0.f, 0.f, 0.f, 0.f};
    #pragma unroll
    for (int sub = 0; sub < 2; ++sub)
      #pragma unroll
      for (int ds = 0; ds < 4; ++ds)
        st[sub] = __builtin_amdgcn_mfma_f32_16x16x32_bf16(kf[sub][ds], qf[ds], st[sub], 0, 0, 0);

    float s[8];
    #pragma unroll
    for (int sub = 0; sub < 2; ++sub) {
      #pragma unroll
      for (int r = 0; r < 4; ++r) {
        float sv = st[sub][r] * SCALE2;
        if (needmask) {
          int p = p0 + sub * 16 + g * 4 + r;
          bool ok = anti ? (p >= tq + 2049) : (p <= tq);
          sv = ok ? sv : -INFINITY;
        }
        s[sub * 4 + r] = sv;
      }
    }

    // online softmax (4-lane-group reduce over key axis)
    float mt = s[0];
    #pragma unroll
    for (int i = 1; i < 8; ++i) mt = fmaxf(mt, s[i]);
    mt = fmaxf(mt, __shfl_xor(mt, 16));
    mt = fmaxf(mt, __shfl_xor(mt, 32));
    float mnew = fmaxf(m_run, mt);
    float fsc  = __builtin_amdgcn_exp2f(m_run - mnew);
    float pv[8];
    float ps = 0.f;
    #pragma unroll
    for (int i = 0; i < 8; ++i) { pv[i] = __builtin_amdgcn_exp2f(s[i] - mnew); ps += pv[i]; }
    ps += __shfl_xor(ps, 16);
    ps += __shfl_xor(ps, 32);
    l_run = l_run * fsc + ps;
    m_run = mnew;
    #pragma unroll
    for (int i = 0; i < 8; ++i) acc[i] *= fsc;

    // P^T -> LDS, then read back in B-fragment layout
    unsigned lo0 = (unsigned)f2bf(pv[0]) | ((unsigned)f2bf(pv[1]) << 16);
    unsigned hi0 = (unsigned)f2bf(pv[2]) | ((unsigned)f2bf(pv[3]) << 16);
    unsigned lo1 = (unsigned)f2bf(pv[4]) | ((unsigned)f2bf(pv[5]) << 16);
    unsigned hi1 = (unsigned)f2bf(pv[6]) | ((unsigned)f2bf(pv[7]) << 16);
    *(uint2*)(prow + g * 4)      = make_uint2(lo0, hi0);
    *(uint2*)(prow + 16 + g * 4) = make_uint2(lo1, hi1);
    short8 pf = *(const short8*)(prow + g * 8);

    // O^T += V^T * P^T : D[d][q]
    #pragma unroll
    for (int db = 0; db < 8; ++db)
      acc[db] = __builtin_amdgcn_mfma_f32_16x16x32_bf16(vf[db], pf, acc[db], 0, 0, 0);
  };

  // enumerate this tile's key-steps; wave w takes s = w, w+4, ...
  int cbase, nc, abeg = 0, na = 0;
  if (tw < T_LOCAL / 2) {
    cbase = 0;
    nc = ((tw + 15) >> 5) + 1;
  } else {
    cbase = 1024;
    nc = ((tw + 15 - 1024) >> 5) + 1;
    abeg = (tw + 2049) & ~31;
    na = ((4064 - abeg) >> 5) + 1;
  }
  const int ntot = nc + na;
  for (int s = w; s < ntot; s += 4) {
    if (s < nc) {
      int p0 = cbase + (s << 5);
      tile_step(p0, p0 + 31 > tw, false);
    } else {
      int p0 = abeg + ((s - nc) << 5);
      tile_step(p0, p0 < tw + 2064, true);
    }
  }

  // ---- cross-wave merge (3 serial rounds through one LDS buffer) ----
  #pragma unroll 1
  for (int r = 1; r < 4; ++r) {
    if (w == r) {
      if (g == 0) { Ml[0][qcol] = m_run; Ml[1][qcol] = l_run; }
      #pragma unroll
      for (int db = 0; db < 8; ++db)
        *(f32x4*)&Obuf[qcol][db * 16 + 4 * g] = acc[db];
    }
    __syncthreads();
    if (w == 0) {
      float mr = Ml[0][qcol], lr = Ml[1][qcol];
      float mnew = fmaxf(m_run, mr);
      float f0 = __builtin_amdgcn_exp2f(m_run - mnew);
      float fr = __builtin_amdgcn_exp2f(mr - mnew);
      l_run = l_run * f0 + lr * fr;
      m_run = mnew;
      #pragma unroll
      for (int db = 0; db < 8; ++db) {
        f32x4 o = *(const f32x4*)&Obuf[qcol][db * 16 + 4 * g];
        acc[db] = acc[db] * f0 + o * fr;
      }
    }
    __syncthreads();
  }

  if (w == 0) {
    float inv = 1.0f / l_run;
    float* ob = Out + (size_t)tq * (NQ * HN) + head * HN + g * 4;
    #pragma unroll
    for (int db = 0; db < 8; ++db) {
      float4 o;
      o.x = acc[db][0] * inv; o.y = acc[db][1] * inv;
      o.z = acc[db][2] * inv; o.w = acc[db][3] * inv;
      *(float4*)(ob + db * 16) = o;
    }
  }
}

extern "C" void kernel_launch(void* const* d_in, const int* in_sizes, int n_in,
                              void* d_out, int out_size, void* d_ws, size_t ws_size,
                              hipStream_t stream) {
  const float* Q = (const float*)d_in[0];
  const float* K = (const float*)d_in[1];
  const float* V = (const float*)d_in[2];
  float* Out = (float*)d_out;

  ushort* Kb = (ushort*)d_ws;                         // 8 MB
  ushort* Vt = Kb + (size_t)S_GLOBAL * NK * HN;       // 8 MB

  k_convert<<<dim3((S_GLOBAL * NK * HN) / (256 * 4)), dim3(256), 0, stream>>>(K, Kb);
  v_transpose<<<dim3(NK * 2 * (S_GLOBAL / 64)), dim3(256), 0, stream>>>(V, Vt);
  attn_kernel<<<dim3(16 * 128), dim3(256), 0, stream>>>(Q, Kb, Vt, Out);
}

// Round 8
// 218.566 us; speedup vs baseline: 1.3709x; 1.0054x over previous
//
#include <hip/hip_runtime.h>
#include <hip/hip_bf16.h>

#define T_LOCAL 2048
#define S_GLOBAL 4096
#define NQ 16
#define NK 8
#define HN 128

// 128^-0.5 * log2(e)
#define SCALE2 0.12753102541996022f

typedef __attribute__((ext_vector_type(8))) short short8;
typedef __attribute__((ext_vector_type(4))) float f32x4;

static __device__ __forceinline__ ushort f2bf(float x) {
  unsigned u = __builtin_bit_cast(unsigned, x);
  unsigned r = (u + 0x7fffu + ((u >> 16) & 1u)) >> 16;
  return (ushort)r;
}

// ---- pre-pass 1: K f32 -> bf16 (same layout [S][NK][HN]) ----
__global__ void k_convert(const float* __restrict__ K, ushort* __restrict__ Kb) {
  size_t i = ((size_t)blockIdx.x * 256 + threadIdx.x) * 4;
  float4 v = *(const float4*)(K + i);
  ushort4 o;
  o.x = f2bf(v.x); o.y = f2bf(v.y); o.z = f2bf(v.z); o.w = f2bf(v.w);
  *(ushort4*)(Kb + i) = o;
}

// ---- pre-pass 2: V f32 [S][NK][HN] -> Vt bf16 [NK][HN][S] (per-head transpose) ----
__global__ void v_transpose(const float* __restrict__ V, ushort* __restrict__ Vt) {
  int bid = blockIdx.x;            // 8 heads * 2 d-tiles * 64 p-tiles = 1024
  int h  = bid >> 7;
  int r  = bid & 127;
  int d0 = (r >> 6) << 6;          // 0 or 64
  int p0 = (r & 63) << 6;          // 0..4032
  __shared__ ushort tile[64][72];  // [d_local][p_local], padded
  int tx = threadIdx.x & 15, ty = threadIdx.x >> 4;
  #pragma unroll
  for (int it = 0; it < 4; ++it) {
    int p = p0 + it * 16 + ty;
    int d = tx * 4;
    float4 v = *(const float4*)(V + ((size_t)p * NK + h) * HN + d0 + d);
    tile[d + 0][it * 16 + ty] = f2bf(v.x);
    tile[d + 1][it * 16 + ty] = f2bf(v.y);
    tile[d + 2][it * 16 + ty] = f2bf(v.z);
    tile[d + 3][it * 16 + ty] = f2bf(v.w);
  }
  __syncthreads();
  #pragma unroll
  for (int it = 0; it < 4; ++it) {
    int d  = it * 16 + ty;
    int pb = tx * 4;
    ushort4 o;
    o.x = tile[d][pb + 0]; o.y = tile[d][pb + 1];
    o.z = tile[d][pb + 2]; o.w = tile[d][pb + 3];
    *(ushort4*)(Vt + ((size_t)h * HN + d0 + d) * S_GLOBAL + p0 + pb) = o;
  }
}

// ---- main attention kernel ----
// grid: 2048 blocks, 256 threads (4 waves), split-K across waves.
// Block mapping gives kvh == XCD (bid % 8): all blocks touching one K/V
// head-pair (2 MB bf16) land on one XCD -> K/V stays L2-resident instead of
// thrashing to Infinity Cache (round-7 wall: ~800 MB fragment traffic at
// 5.9 TB/s ~= L3 ceiling).
__global__ __launch_bounds__(256, 4)
void attn_kernel(const float* __restrict__ Q, const ushort* __restrict__ Kb,
                 const ushort* __restrict__ Vt, float* __restrict__ Out) {
  __shared__ ushort Pl[4][16][56];   // per-wave P^T staging
  __shared__ float Obuf[16][132];    // merge buffer [q][d], padded
  __shared__ float Ml[2][16];        // merge m,l per q

  const int lane = threadIdx.x & 63;
  const int w    = threadIdx.x >> 6;   // chunk id
  const int qcol = lane & 15;
  const int g    = lane >> 4;

  const int bid  = blockIdx.x;
  const int x    = bid & 7;          // XCD (assumes round-robin dispatch)
  const int s    = bid >> 3;         // 0..255 within XCD
  const int kvh  = x;                // K/V head-pair pinned to this XCD's L2
  const int head = 2 * x + (s & 1);
  const int u    = s >> 1;           // 0..127
  // interleave light (first-half) / heavy (second-half) q-tiles along the
  // within-XCD dispatch order for CU load balance.
  const int tile = (u & 1) ? 64 + (u >> 1) : (u >> 1);
  const int tw   = tile << 4;
  const int tq   = tw + qcol;        // this lane's q row (local index)

  // Q fragments (B operand: col = q, k-slice = d)
  short8 qf[4];
  {
    const float* qb = Q + ((size_t)tq * NQ + head) * HN;
    #pragma unroll
    for (int ds = 0; ds < 4; ++ds) {
      const float4* p4 = (const float4*)(qb + ds * 32 + g * 8);
      float4 a = p4[0], b = p4[1];
      short8 f;
      f[0] = f2bf(a.x); f[1] = f2bf(a.y); f[2] = f2bf(a.z); f[3] = f2bf(a.w);
      f[4] = f2bf(b.x); f[5] = f2bf(b.y); f[6] = f2bf(b.z); f[7] = f2bf(b.w);
      qf[ds] = f;
    }
  }

  f32x4 acc[8];
  #pragma unroll
  for (int i = 0; i < 8; ++i) acc[i] = (f32x4){0.f, 0.f, 0.f, 0.f};
  float m_run = -1e30f, l_run = 0.f;

  const ushort* Vrow = Vt + (size_t)kvh * HN * S_GLOBAL;
  ushort* prow = &Pl[w][qcol][0];

  auto tile_step = [&](int p0, bool needmask, bool anti) {
    // K A-fragments: row = key (qcol), k-slice = d
    short8 kf[2][4];
    #pragma unroll
    for (int sub = 0; sub < 2; ++sub) {
      const ushort* kp = Kb + ((size_t)(p0 + sub * 16 + qcol) * NK + kvh) * HN + g * 8;
      #pragma unroll
      for (int ds = 0; ds < 4; ++ds)
        kf[sub][ds] = *(const short8*)(kp + ds * 32);
    }
    // V^T A-fragments: row = d (qcol), k-slice = keys
    short8 vf[8];
    #pragma unroll
    for (int db = 0; db < 8; ++db)
      vf[db] = *(const short8*)(Vrow + (size_t)(db * 16 + qcol) * S_GLOBAL + p0 + g * 8);

    // S^T = K * Q^T : D[key][q]
    f32x4 st[2];
    st[0] = (f32x4){0.f, 0.f, 0.f, 0.f};
    st[1] = (f32x4){0.f, 0.f, 0.f, 0.f};
    #pragma unroll
    for (int sub = 0; sub < 2; ++sub)
      #pragma unroll
      for (int ds = 0; ds < 4; ++ds)
        st[sub] = __builtin_amdgcn_mfma_f32_16x16x32_bf16(kf[sub][ds], qf[ds], st[sub], 0, 0, 0);

    float s_[8];
    #pragma unroll
    for (int sub = 0; sub < 2; ++sub) {
      #pragma unroll
      for (int r = 0; r < 4; ++r) {
        float sv = st[sub][r] * SCALE2;
        if (needmask) {
          int p = p0 + sub * 16 + g * 4 + r;
          bool ok = anti ? (p >= tq + 2049) : (p <= tq);
          sv = ok ? sv : -INFINITY;
        }
        s_[sub * 4 + r] = sv;
      }
    }

    // online softmax (4-lane-group reduce over key axis)
    float mt = s_[0];
    #pragma unroll
    for (int i = 1; i < 8; ++i) mt = fmaxf(mt, s_[i]);
    mt = fmaxf(mt, __shfl_xor(mt, 16));
    mt = fmaxf(mt, __shfl_xor(mt, 32));
    float mnew = fmaxf(m_run, mt);
    float fsc  = __builtin_amdgcn_exp2f(m_run - mnew);
    float pv[8];
    float ps = 0.f;
    #pragma unroll
    for (int i = 0; i < 8; ++i) { pv[i] = __builtin_amdgcn_exp2f(s_[i] - mnew); ps += pv[i]; }
    ps += __shfl_xor(ps, 16);
    ps += __shfl_xor(ps, 32);
    l_run = l_run * fsc + ps;
    m_run = mnew;
    #pragma unroll
    for (int i = 0; i < 8; ++i) acc[i] *= fsc;

    // P^T -> LDS, then read back in B-fragment layout
    unsigned lo0 = (unsigned)f2bf(pv[0]) | ((unsigned)f2bf(pv[1]) << 16);
    unsigned hi0 = (unsigned)f2bf(pv[2]) | ((unsigned)f2bf(pv[3]) << 16);
    unsigned lo1 = (unsigned)f2bf(pv[4]) | ((unsigned)f2bf(pv[5]) << 16);
    unsigned hi1 = (unsigned)f2bf(pv[6]) | ((unsigned)f2bf(pv[7]) << 16);
    *(uint2*)(prow + g * 4)      = make_uint2(lo0, hi0);
    *(uint2*)(prow + 16 + g * 4) = make_uint2(lo1, hi1);
    short8 pf = *(const short8*)(prow + g * 8);

    // O^T += V^T * P^T : D[d][q]
    #pragma unroll
    for (int db = 0; db < 8; ++db)
      acc[db] = __builtin_amdgcn_mfma_f32_16x16x32_bf16(vf[db], pf, acc[db], 0, 0, 0);
  };

  // enumerate this tile's key-steps; wave w takes s = w, w+4, ...
  int cbase, nc, abeg = 0, na = 0;
  if (tw < T_LOCAL / 2) {
    cbase = 0;
    nc = ((tw + 15) >> 5) + 1;
  } else {
    cbase = 1024;
    nc = ((tw + 15 - 1024) >> 5) + 1;
    abeg = (tw + 2049) & ~31;
    na = ((4064 - abeg) >> 5) + 1;
  }
  const int ntot = nc + na;
  for (int st_i = w; st_i < ntot; st_i += 4) {
    if (st_i < nc) {
      int p0 = cbase + (st_i << 5);
      tile_step(p0, p0 + 31 > tw, false);
    } else {
      int p0 = abeg + ((st_i - nc) << 5);
      tile_step(p0, p0 < tw + 2064, true);
    }
  }

  // ---- cross-wave merge (3 serial rounds through one LDS buffer) ----
  #pragma unroll 1
  for (int r = 1; r < 4; ++r) {
    if (w == r) {
      if (g == 0) { Ml[0][qcol] = m_run; Ml[1][qcol] = l_run; }
      #pragma unroll
      for (int db = 0; db < 8; ++db)
        *(f32x4*)&Obuf[qcol][db * 16 + 4 * g] = acc[db];
    }
    __syncthreads();
    if (w == 0) {
      float mr = Ml[0][qcol], lr = Ml[1][qcol];
      float mnew = fmaxf(m_run, mr);
      float f0 = __builtin_amdgcn_exp2f(m_run - mnew);
      float fr = __builtin_amdgcn_exp2f(mr - mnew);
      l_run = l_run * f0 + lr * fr;
      m_run = mnew;
      #pragma unroll
      for (int db = 0; db < 8; ++db) {
        f32x4 o = *(const f32x4*)&Obuf[qcol][db * 16 + 4 * g];
        acc[db] = acc[db] * f0 + o * fr;
      }
    }
    __syncthreads();
  }

  if (w == 0) {
    float inv = 1.0f / l_run;
    float* ob = Out + (size_t)tq * (NQ * HN) + head * HN + g * 4;
    #pragma unroll
    for (int db = 0; db < 8; ++db) {
      float4 o;
      o.x = acc[db][0] * inv; o.y = acc[db][1] * inv;
      o.z = acc[db][2] * inv; o.w = acc[db][3] * inv;
      *(float4*)(ob + db * 16) = o;
    }
  }
}

extern "C" void kernel_launch(void* const* d_in, const int* in_sizes, int n_in,
                              void* d_out, int out_size, void* d_ws, size_t ws_size,
                              hipStream_t stream) {
  const float* Q = (const float*)d_in[0];
  const float* K = (const float*)d_in[1];
  const float* V = (const float*)d_in[2];
  float* Out = (float*)d_out;

  ushort* Kb = (ushort*)d_ws;                         // 8 MB
  ushort* Vt = Kb + (size_t)S_GLOBAL * NK * HN;       // 8 MB

  k_convert<<<dim3((S_GLOBAL * NK * HN) / (256 * 4)), dim3(256), 0, stream>>>(K, Kb);
  v_transpose<<<dim3(NK * 2 * (S_GLOBAL / 64)), dim3(256), 0, stream>>>(V, Vt);
  attn_kernel<<<dim3(2048), dim3(256), 0, stream>>>(Q, Kb, Vt, Out);
}

// Round 10
// 146.826 us; speedup vs baseline: 2.0408x; 1.4886x over previous
//
#include <hip/hip_runtime.h>
#include <hip/hip_bf16.h>

#define T_LOCAL 2048
#define S_GLOBAL 4096
#define NQ 16
#define NK 8
#define HN 128

// 128^-0.5 * log2(e)
#define SCALE2 0.12753102541996022f

typedef __attribute__((ext_vector_type(8))) short short8;
typedef __attribute__((ext_vector_type(4))) float f32x4;

static __device__ __forceinline__ ushort f2bf(float x) {
  unsigned u = __builtin_bit_cast(unsigned, x);
  unsigned r = (u + 0x7fffu + ((u >> 16) & 1u)) >> 16;
  return (ushort)r;
}

static __device__ __forceinline__ void gload16(const ushort* g, ushort* lds) {
  __builtin_amdgcn_global_load_lds(
      (const __attribute__((address_space(1))) void*)g,
      (__attribute__((address_space(3))) void*)lds, 16, 0, 0);
}

// ---- pre-pass 1: K f32 -> bf16 (same layout [S][NK][HN]) ----
__global__ void k_convert(const float* __restrict__ K, ushort* __restrict__ Kb) {
  size_t i = ((size_t)blockIdx.x * 256 + threadIdx.x) * 4;
  float4 v = *(const float4*)(K + i);
  ushort4 o;
  o.x = f2bf(v.x); o.y = f2bf(v.y); o.z = f2bf(v.z); o.w = f2bf(v.w);
  *(ushort4*)(Kb + i) = o;
}

// ---- pre-pass 2: V f32 [S][NK][HN] -> Vt bf16 [NK][HN][S] (per-head transpose) ----
__global__ void v_transpose(const float* __restrict__ V, ushort* __restrict__ Vt) {
  int bid = blockIdx.x;            // 8 heads * 2 d-tiles * 64 p-tiles = 1024
  int h  = bid >> 7;
  int r  = bid & 127;
  int d0 = (r >> 6) << 6;          // 0 or 64
  int p0 = (r & 63) << 6;          // 0..4032
  __shared__ ushort tile[64][72];  // [d_local][p_local], padded
  int tx = threadIdx.x & 15, ty = threadIdx.x >> 4;
  #pragma unroll
  for (int it = 0; it < 4; ++it) {
    int p = p0 + it * 16 + ty;
    int d = tx * 4;
    float4 v = *(const float4*)(V + ((size_t)p * NK + h) * HN + d0 + d);
    tile[d + 0][it * 16 + ty] = f2bf(v.x);
    tile[d + 1][it * 16 + ty] = f2bf(v.y);
    tile[d + 2][it * 16 + ty] = f2bf(v.z);
    tile[d + 3][it * 16 + ty] = f2bf(v.w);
  }
  __syncthreads();
  #pragma unroll
  for (int it = 0; it < 4; ++it) {
    int d  = it * 16 + ty;
    int pb = tx * 4;
    ushort4 o;
    o.x = tile[d][pb + 0]; o.y = tile[d][pb + 1];
    o.z = tile[d][pb + 2]; o.w = tile[d][pb + 3];
    *(ushort4*)(Vt + ((size_t)h * HN + d0 + d) * S_GLOBAL + p0 + pb) = o;
  }
}

// ---- main attention kernel ----
// grid 512: bid = kvh(8, ==XCD) x [head-half(2) x tile-slot(32)].
// Block = one head x 64 q-rows (wave w owns rows tb+16w..+15).
// Per 64-key chunk: K(16KB)+V^T(16KB) staged to LDS via global_load_lds with
// pre-swizzled global source (XOR swizzle: 16B-unit ^= row&7) so ds_read_b128
// is bank-even. Double-buffered, counted vmcnt(8), raw s_barrier (no drain).
__global__ __launch_bounds__(256, 4)
void attn_kernel(const float* __restrict__ Q, const ushort* __restrict__ Kb,
                 const ushort* __restrict__ Vt, float* __restrict__ Out) {
  __shared__ ushort Klds[2][64 * 128];   // 2 x 16 KB, row = 64 keys x 256B
  __shared__ ushort Vlds[2][128 * 64];   // 2 x 16 KB, row = 128 d x 128B
  __shared__ ushort Pl[4][16][56];       // per-wave P^T staging

  const int lane = threadIdx.x & 63;
  const int w    = threadIdx.x >> 6;
  const int qcol = lane & 15;
  const int g    = lane >> 4;

  const int bid  = blockIdx.x;
  const int kvh  = bid & 7;              // K/V head pinned to XCD L2
  const int j    = bid >> 3;             // 0..63
  const int head = 2 * kvh + (j & 1);
  const int slot = j >> 1;               // 0..31, light/heavy interleaved
  const int Tt   = (slot & 1) ? 16 + (slot >> 1) : (slot >> 1);  // 0..31
  const int tb   = Tt << 6;
  const int tw   = tb + w * 16;
  const int tq   = tw + qcol;

  // chunk list: light = chunks [0..Tt]; heavy = causal [16..Tt] + anti [Tt+32..63]
  int c0, nC, a0 = 0, n;
  if (tb < 1024) { c0 = 0; nC = Tt + 1; n = nC; }
  else { c0 = 16; nC = Tt - 15; a0 = Tt + 32; n = nC + (32 - Tt); }

  // Q fragments (B operand: col = q, k-slice = d)
  short8 qf[4];
  {
    const float* qb = Q + ((size_t)tq * NQ + head) * HN;
    #pragma unroll
    for (int ds = 0; ds < 4; ++ds) {
      const float4* p4 = (const float4*)(qb + ds * 32 + g * 8);
      float4 a = p4[0], b = p4[1];
      short8 f;
      f[0] = f2bf(a.x); f[1] = f2bf(a.y); f[2] = f2bf(a.z); f[3] = f2bf(a.w);
      f[4] = f2bf(b.x); f[5] = f2bf(b.y); f[6] = f2bf(b.z); f[7] = f2bf(b.w);
      qf[ds] = f;
    }
  }
  // drain Q loads so vmcnt counting below sees only staging loads
  asm volatile("s_waitcnt vmcnt(0)" ::: "memory");

  f32x4 acc[8];
  #pragma unroll
  for (int i = 0; i < 8; ++i) acc[i] = (f32x4){0.f, 0.f, 0.f, 0.f};
  float m_run = -1e30f, l_run = 0.f;

  ushort* prow = &Pl[w][qcol][0];
  const int rx = (qcol & 7) << 4;        // read-side swizzle term

  auto chunk_p0 = [&](int i) {
    return ((i < nC) ? (c0 + i) : (a0 + (i - nC))) << 6;
  };

  // stage one 64-key chunk (8 gload16 per wave: 4 K + 4 V)
  auto stage = [&](int b, int p0) {
    #pragma unroll
    for (int t = 0; t < 4; ++t) {
      int idx = (w * 4 + t) * 64 + lane;          // 0..1023
      int row = idx >> 4;                          // key row 0..63
      int cu  = (idx & 15) ^ (row & 7);            // swizzled 16B col unit
      gload16(Kb + ((size_t)(p0 + row) * NK + kvh) * HN + cu * 8,
              &Klds[b][(w * 4 + t) * 512]);
    }
    #pragma unroll
    for (int t = 0; t < 4; ++t) {
      int idx = (w * 4 + t) * 64 + lane;
      int d   = idx >> 3;                          // d row 0..127
      int pu  = (idx & 7) ^ ((idx >> 3) & 7);      // swizzled 16B p unit
      gload16(Vt + ((size_t)kvh * HN + d) * S_GLOBAL + p0 + pu * 8,
              &Vlds[b][(w * 4 + t) * 512]);
    }
  };

  stage(0, chunk_p0(0));

  for (int c = 0; c < n; ++c) {
    if (c + 1 < n) {
      stage((c + 1) & 1, chunk_p0(c + 1));
      asm volatile("s_waitcnt vmcnt(8)" ::: "memory");   // current chunk landed
    } else {
      asm volatile("s_waitcnt vmcnt(0)" ::: "memory");
    }
    __builtin_amdgcn_s_barrier();

    const int p0   = chunk_p0(c);
    const bool anti = p0 >= 2048;
    const char* Klc = (const char*)Klds[c & 1];
    const char* Vlc = (const char*)Vlds[c & 1];

    #pragma unroll
    for (int psub = 0; psub < 2; ++psub) {
      const int p0s = p0 + psub * 32;
      const bool activ = anti ? (p0s + 31 >= tw + 2049) : (p0s <= tw + 15);
      if (activ) {
        const bool needmask = anti ? (p0s < tw + 2064) : (p0s + 31 > tw);

        // K fragments from LDS (swizzled, bank-even)
        short8 kf[2][4];
        #pragma unroll
        for (int sub = 0; sub < 2; ++sub) {
          const int rbase = (psub * 32 + sub * 16 + qcol) * 256;
          #pragma unroll
          for (int ds = 0; ds < 4; ++ds)
            kf[sub][ds] = *(const short8*)(Klc + rbase + ((ds * 64 + g * 16) ^ rx));
        }

        // S^T = K * Q^T
        f32x4 st[2];
        st[0] = (f32x4){0.f, 0.f, 0.f, 0.f};
        st[1] = (f32x4){0.f, 0.f, 0.f, 0.f};
        #pragma unroll
        for (int sub = 0; sub < 2; ++sub)
          #pragma unroll
          for (int ds = 0; ds < 4; ++ds)
            st[sub] = __builtin_amdgcn_mfma_f32_16x16x32_bf16(kf[sub][ds], qf[ds], st[sub], 0, 0, 0);

        float s_[8];
        #pragma unroll
        for (int sub = 0; sub < 2; ++sub) {
          #pragma unroll
          for (int r = 0; r < 4; ++r) {
            float sv = st[sub][r] * SCALE2;
            if (needmask) {
              int p = p0s + sub * 16 + g * 4 + r;
              bool ok = anti ? (p >= tq + 2049) : (p <= tq);
              sv = ok ? sv : -INFINITY;
            }
            s_[sub * 4 + r] = sv;
          }
        }

        // online softmax (4-lane-group reduce over key axis)
        float mt = s_[0];
        #pragma unroll
        for (int i = 1; i < 8; ++i) mt = fmaxf(mt, s_[i]);
        mt = fmaxf(mt, __shfl_xor(mt, 16));
        mt = fmaxf(mt, __shfl_xor(mt, 32));
        float mnew = fmaxf(m_run, mt);
        float fsc  = __builtin_amdgcn_exp2f(m_run - mnew);
        float pv[8];
        float ps = 0.f;
        #pragma unroll
        for (int i = 0; i < 8; ++i) { pv[i] = __builtin_amdgcn_exp2f(s_[i] - mnew); ps += pv[i]; }
        ps += __shfl_xor(ps, 16);
        ps += __shfl_xor(ps, 32);
        l_run = l_run * fsc + ps;
        m_run = mnew;
        #pragma unroll
        for (int i = 0; i < 8; ++i) acc[i] *= fsc;

        // P^T -> LDS roundtrip into B-fragment layout
        unsigned lo0 = (unsigned)f2bf(pv[0]) | ((unsigned)f2bf(pv[1]) << 16);
        unsigned hi0 = (unsigned)f2bf(pv[2]) | ((unsigned)f2bf(pv[3]) << 16);
        unsigned lo1 = (unsigned)f2bf(pv[4]) | ((unsigned)f2bf(pv[5]) << 16);
        unsigned hi1 = (unsigned)f2bf(pv[6]) | ((unsigned)f2bf(pv[7]) << 16);
        *(uint2*)(prow + g * 4)      = make_uint2(lo0, hi0);
        *(uint2*)(prow + 16 + g * 4) = make_uint2(lo1, hi1);
        short8 pf = *(const short8*)(prow + g * 8);

        // V^T fragments from LDS
        short8 vf[8];
        #pragma unroll
        for (int db = 0; db < 8; ++db)
          vf[db] = *(const short8*)(Vlc + (db * 16 + qcol) * 128 + ((psub * 64 + g * 16) ^ rx));

        // O^T += V^T * P^T
        #pragma unroll
        for (int db = 0; db < 8; ++db)
          acc[db] = __builtin_amdgcn_mfma_f32_16x16x32_bf16(vf[db], pf, acc[db], 0, 0, 0);
      }
    }
    __builtin_amdgcn_s_barrier();
  }

  // epilogue: wave owns its 16 q-rows, direct write
  float inv = 1.0f / l_run;
  float* ob = Out + (size_t)tq * (NQ * HN) + head * HN + g * 4;
  #pragma unroll
  for (int db = 0; db < 8; ++db) {
    float4 o;
    o.x = acc[db][0] * inv; o.y = acc[db][1] * inv;
    o.z = acc[db][2] * inv; o.w = acc[db][3] * inv;
    *(float4*)(ob + db * 16) = o;
  }
}

extern "C" void kernel_launch(void* const* d_in, const int* in_sizes, int n_in,
                              void* d_out, int out_size, void* d_ws, size_t ws_size,
                              hipStream_t stream) {
  const float* Q = (const float*)d_in[0];
  const float* K = (const float*)d_in[1];
  const float* V = (const float*)d_in[2];
  float* Out = (float*)d_out;

  ushort* Kb = (ushort*)d_ws;                         // 8 MB
  ushort* Vt = Kb + (size_t)S_GLOBAL * NK * HN;       // 8 MB

  k_convert<<<dim3((S_GLOBAL * NK * HN) / (256 * 4)), dim3(256), 0, stream>>>(K, Kb);
  v_transpose<<<dim3(NK * 2 * (S_GLOBAL / 64)), dim3(256), 0, stream>>>(V, Vt);
  attn_kernel<<<dim3(512), dim3(256), 0, stream>>>(Q, Kb, Vt, Out);
}

// Round 12
// 140.196 us; speedup vs baseline: 2.1373x; 1.0473x over previous
//
#include <hip/hip_runtime.h>
#include <hip/hip_bf16.h>

#define T_LOCAL 2048
#define S_GLOBAL 4096
#define NQ 16
#define NK 8
#define HN 128

// 128^-0.5 * log2(e)
#define SCALE2 0.12753102541996022f

typedef __attribute__((ext_vector_type(8))) short short8;
typedef __attribute__((ext_vector_type(4))) float f32x4;

static __device__ __forceinline__ ushort f2bf(float x) {
  unsigned u = __builtin_bit_cast(unsigned, x);
  unsigned r = (u + 0x7fffu + ((u >> 16) & 1u)) >> 16;
  return (ushort)r;
}

static __device__ __forceinline__ void gload16(const ushort* g, ushort* lds) {
  __builtin_amdgcn_global_load_lds(
      (const __attribute__((address_space(1))) void*)g,
      (__attribute__((address_space(3))) void*)lds, 16, 0, 0);
}

// ---- pre-pass 1: K f32 -> bf16 (same layout [S][NK][HN]) ----
__global__ void k_convert(const float* __restrict__ K, ushort* __restrict__ Kb) {
  size_t i = ((size_t)blockIdx.x * 256 + threadIdx.x) * 4;
  float4 v = *(const float4*)(K + i);
  ushort4 o;
  o.x = f2bf(v.x); o.y = f2bf(v.y); o.z = f2bf(v.z); o.w = f2bf(v.w);
  *(ushort4*)(Kb + i) = o;
}

// ---- pre-pass 2: V f32 [S][NK][HN] -> Vt bf16 [NK][HN][S] (per-head transpose) ----
__global__ void v_transpose(const float* __restrict__ V, ushort* __restrict__ Vt) {
  int bid = blockIdx.x;            // 8 heads * 2 d-tiles * 64 p-tiles = 1024
  int h  = bid >> 7;
  int r  = bid & 127;
  int d0 = (r >> 6) << 6;          // 0 or 64
  int p0 = (r & 63) << 6;          // 0..4032
  __shared__ ushort tile[64][72];  // [d_local][p_local], padded
  int tx = threadIdx.x & 15, ty = threadIdx.x >> 4;
  #pragma unroll
  for (int it = 0; it < 4; ++it) {
    int p = p0 + it * 16 + ty;
    int d = tx * 4;
    float4 v = *(const float4*)(V + ((size_t)p * NK + h) * HN + d0 + d);
    tile[d + 0][it * 16 + ty] = f2bf(v.x);
    tile[d + 1][it * 16 + ty] = f2bf(v.y);
    tile[d + 2][it * 16 + ty] = f2bf(v.z);
    tile[d + 3][it * 16 + ty] = f2bf(v.w);
  }
  __syncthreads();
  #pragma unroll
  for (int it = 0; it < 4; ++it) {
    int d  = it * 16 + ty;
    int pb = tx * 4;
    ushort4 o;
    o.x = tile[d][pb + 0]; o.y = tile[d][pb + 1];
    o.z = tile[d][pb + 2]; o.w = tile[d][pb + 3];
    *(ushort4*)(Vt + ((size_t)h * HN + d0 + d) * S_GLOBAL + p0 + pb) = o;
  }
}

// ---- main attention kernel ----
// grid 512, 512 threads (8 waves). Wave (qg,ks): qg owns 16 q-rows,
// ks owns one 32-key half of each 64-key chunk (2-way key split, merged at
// end through reused Klds). K/V chunk staged once to LDS (global_load_lds,
// pre-swizzled source), double-buffered, counted vmcnt(4), raw s_barrier.
__global__ __launch_bounds__(512, 4)
void attn_kernel(const float* __restrict__ Q, const ushort* __restrict__ Kb,
                 const ushort* __restrict__ Vt, float* __restrict__ Out) {
  __shared__ ushort Klds[2][64 * 128];   // 2 x 16 KB
  __shared__ ushort Vlds[2][128 * 64];   // 2 x 16 KB
  __shared__ ushort Pl[8][16][56];       // per-wave P^T staging (14 KB)

  const int lane = threadIdx.x & 63;
  const int w    = threadIdx.x >> 6;     // 0..7
  const int qg   = w & 3;                // q-row group
  const int ks   = w >> 2;               // key-half 0/1
  const int qcol = lane & 15;
  const int g    = lane >> 4;

  const int bid  = blockIdx.x;
  const int kvh  = bid & 7;              // K/V head pinned to XCD L2
  const int j    = bid >> 3;             // 0..63
  const int head = 2 * kvh + (j & 1);
  const int slot = j >> 1;               // 0..31, light/heavy interleaved
  const int Tt   = (slot & 1) ? 16 + (slot >> 1) : (slot >> 1);  // 0..31
  const int tb   = Tt << 6;
  const int tw   = tb + qg * 16;
  const int tq   = tw + qcol;

  // chunk list: light = [0..Tt]; heavy = causal [16..Tt] + anti [Tt+32..63]
  int c0, nC, a0 = 0, n;
  if (tb < 1024) { c0 = 0; nC = Tt + 1; n = nC; }
  else { c0 = 16; nC = Tt - 15; a0 = Tt + 32; n = nC + (32 - Tt); }

  // Q fragments (B operand: col = q, k-slice = d)
  short8 qf[4];
  {
    const float* qb = Q + ((size_t)tq * NQ + head) * HN;
    #pragma unroll
    for (int ds = 0; ds < 4; ++ds) {
      const float4* p4 = (const float4*)(qb + ds * 32 + g * 8);
      float4 a = p4[0], b = p4[1];
      short8 f;
      f[0] = f2bf(a.x); f[1] = f2bf(a.y); f[2] = f2bf(a.z); f[3] = f2bf(a.w);
      f[4] = f2bf(b.x); f[5] = f2bf(b.y); f[6] = f2bf(b.z); f[7] = f2bf(b.w);
      qf[ds] = f;
    }
  }
  // drain Q loads so vmcnt counting below sees only staging loads
  asm volatile("s_waitcnt vmcnt(0)" ::: "memory");

  f32x4 acc[8];
  #pragma unroll
  for (int i = 0; i < 8; ++i) acc[i] = (f32x4){0.f, 0.f, 0.f, 0.f};
  float m_run = -1e30f, l_run = 0.f;

  ushort* prow = &Pl[w][qcol][0];
  const int rx = (qcol & 7) << 4;        // read-side swizzle term

  auto chunk_p0 = [&](int i) {
    return ((i < nC) ? (c0 + i) : (a0 + (i - nC))) << 6;
  };

  // stage one 64-key chunk (4 gload16 per wave: 2 K + 2 V; 8 waves cover all)
  auto stage = [&](int b, int p0) {
    #pragma unroll
    for (int t = 0; t < 2; ++t) {
      int idx = (w * 2 + t) * 64 + lane;          // 0..1023
      int row = idx >> 4;                          // key row 0..63
      int cu  = (idx & 15) ^ (row & 7);            // swizzled 16B col unit
      gload16(Kb + ((size_t)(p0 + row) * NK + kvh) * HN + cu * 8,
              &Klds[b][(w * 2 + t) * 512]);
    }
    #pragma unroll
    for (int t = 0; t < 2; ++t) {
      int idx = (w * 2 + t) * 64 + lane;
      int d   = idx >> 3;                          // d row 0..127
      int pu  = (idx & 7) ^ (d & 7);               // swizzled 16B p unit
      gload16(Vt + ((size_t)kvh * HN + d) * S_GLOBAL + p0 + pu * 8,
              &Vlds[b][(w * 2 + t) * 512]);
    }
  };

  stage(0, chunk_p0(0));

  for (int c = 0; c < n; ++c) {
    if (c + 1 < n) {
      stage((c + 1) & 1, chunk_p0(c + 1));
      asm volatile("s_waitcnt vmcnt(4)" ::: "memory");   // current chunk landed
    } else {
      asm volatile("s_waitcnt vmcnt(0)" ::: "memory");
    }
    __builtin_amdgcn_s_barrier();

    const int p0   = chunk_p0(c);
    const bool anti = p0 >= 2048;
    const char* Klc = (const char*)Klds[c & 1];
    const char* Vlc = (const char*)Vlds[c & 1];

    const int p0s = p0 + ks * 32;   // this wave's 32-key half
    const bool activ = anti ? (p0s + 31 >= tw + 2049) : (p0s <= tw + 15);
    if (activ) {
      const bool needmask = anti ? (p0s < tw + 2064) : (p0s + 31 > tw);

      // K fragments from LDS (swizzled, bank-even)
      short8 kf[2][4];
      #pragma unroll
      for (int sub = 0; sub < 2; ++sub) {
        const int rbase = (ks * 32 + sub * 16 + qcol) * 256;
        #pragma unroll
        for (int ds = 0; ds < 4; ++ds)
          kf[sub][ds] = *(const short8*)(Klc + rbase + ((ds * 64 + g * 16) ^ rx));
      }
      // V^T fragments hoisted early: ds latency overlaps QK MFMA + softmax
      short8 vf[8];
      #pragma unroll
      for (int db = 0; db < 8; ++db)
        vf[db] = *(const short8*)(Vlc + (db * 16 + qcol) * 128 + ((ks * 64 + g * 16) ^ rx));

      // S^T = K * Q^T  (wave's 32 keys)
      f32x4 st[2];
      st[0] = (f32x4){0.f, 0.f, 0.f, 0.f};
      st[1] = (f32x4){0.f, 0.f, 0.f, 0.f};
      #pragma unroll
      for (int sub = 0; sub < 2; ++sub)
        #pragma unroll
        for (int ds = 0; ds < 4; ++ds)
          st[sub] = __builtin_amdgcn_mfma_f32_16x16x32_bf16(kf[sub][ds], qf[ds], st[sub], 0, 0, 0);

      float s_[8];
      #pragma unroll
      for (int sub = 0; sub < 2; ++sub) {
        #pragma unroll
        for (int r = 0; r < 4; ++r) {
          float sv = st[sub][r] * SCALE2;
          if (needmask) {
            int p = p0s + sub * 16 + g * 4 + r;
            bool ok = anti ? (p >= tq + 2049) : (p <= tq);
            sv = ok ? sv : -INFINITY;
          }
          s_[sub * 4 + r] = sv;
        }
      }

      // online softmax (4-lane-group reduce over key axis)
      float mt = s_[0];
      #pragma unroll
      for (int i = 1; i < 8; ++i) mt = fmaxf(mt, s_[i]);
      mt = fmaxf(mt, __shfl_xor(mt, 16));
      mt = fmaxf(mt, __shfl_xor(mt, 32));
      float mnew = fmaxf(m_run, mt);
      float fsc  = __builtin_amdgcn_exp2f(m_run - mnew);
      float pv[8];
      float ps = 0.f;
      #pragma unroll
      for (int i = 0; i < 8; ++i) { pv[i] = __builtin_amdgcn_exp2f(s_[i] - mnew); ps += pv[i]; }
      ps += __shfl_xor(ps, 16);
      ps += __shfl_xor(ps, 32);
      l_run = l_run * fsc + ps;
      m_run = mnew;
      #pragma unroll
      for (int i = 0; i < 8; ++i) acc[i] *= fsc;

      // P^T -> LDS roundtrip into B-fragment layout
      unsigned lo0 = (unsigned)f2bf(pv[0]) | ((unsigned)f2bf(pv[1]) << 16);
      unsigned hi0 = (unsigned)f2bf(pv[2]) | ((unsigned)f2bf(pv[3]) << 16);
      unsigned lo1 = (unsigned)f2bf(pv[4]) | ((unsigned)f2bf(pv[5]) << 16);
      unsigned hi1 = (unsigned)f2bf(pv[6]) | ((unsigned)f2bf(pv[7]) << 16);
      *(uint2*)(prow + g * 4)      = make_uint2(lo0, hi0);
      *(uint2*)(prow + 16 + g * 4) = make_uint2(lo1, hi1);
      short8 pf = *(const short8*)(prow + g * 8);

      // O^T += V^T * P^T  (one MFMA per d-block covers the wave's 32 keys)
      #pragma unroll
      for (int db = 0; db < 8; ++db)
        acc[db] = __builtin_amdgcn_mfma_f32_16x16x32_bf16(vf[db], pf, acc[db], 0, 0, 0);
    }
    __builtin_amdgcn_s_barrier();
  }

  // ---- 2-way key-half merge (ks=1 -> ks=0) through reused Klds ----
  __syncthreads();                       // full fence before overwriting Klds
  float* mb  = (float*)&Klds[0][0];      // [4 qg][16 row][128 d] = 32 KB
  float* mlb = (float*)&Vlds[0][0];      // [4 qg][16 row][2]
  if (ks == 1) {
    if (g == 0) {
      mlb[(qg * 16 + qcol) * 2 + 0] = m_run;
      mlb[(qg * 16 + qcol) * 2 + 1] = l_run;
    }
    #pragma unroll
    for (int db = 0; db < 8; ++db)
      *(f32x4*)&mb[(qg * 16 + qcol) * 128 + db * 16 + g * 4] = acc[db];
  }
  __syncthreads();
  if (ks == 0) {
    float mr = mlb[(qg * 16 + qcol) * 2 + 0];
    float lr = mlb[(qg * 16 + qcol) * 2 + 1];
    float mnew = fmaxf(m_run, mr);
    float f0 = __builtin_amdgcn_exp2f(m_run - mnew);
    float fr = __builtin_amdgcn_exp2f(mr - mnew);
    float inv = 1.0f / (l_run * f0 + lr * fr);
    float* ob = Out + (size_t)tq * (NQ * HN) + head * HN + g * 4;
    #pragma unroll
    for (int db = 0; db < 8; ++db) {
      f32x4 o = *(const f32x4*)&mb[(qg * 16 + qcol) * 128 + db * 16 + g * 4];
      float4 r;
      r.x = (acc[db][0] * f0 + o[0] * fr) * inv;
      r.y = (acc[db][1] * f0 + o[1] * fr) * inv;
      r.z = (acc[db][2] * f0 + o[2] * fr) * inv;
      r.w = (acc[db][3] * f0 + o[3] * fr) * inv;
      *(float4*)(ob + db * 16) = r;
    }
  }
}

extern "C" void kernel_launch(void* const* d_in, const int* in_sizes, int n_in,
                              void* d_out, int out_size, void* d_ws, size_t ws_size,
                              hipStream_t stream) {
  const float* Q = (const float*)d_in[0];
  const float* K = (const float*)d_in[1];
  const float* V = (const float*)d_in[2];
  float* Out = (float*)d_out;

  ushort* Kb = (ushort*)d_ws;                         // 8 MB
  ushort* Vt = Kb + (size_t)S_GLOBAL * NK * HN;       // 8 MB

  k_convert<<<dim3((S_GLOBAL * NK * HN) / (256 * 4)), dim3(256), 0, stream>>>(K, Kb);
  v_transpose<<<dim3(NK * 2 * (S_GLOBAL / 64)), dim3(256), 0, stream>>>(V, Vt);
  attn_kernel<<<dim3(512), dim3(512), 0, stream>>>(Q, Kb, Vt, Out);
}